// Round 16
// baseline (90.993 us; speedup 1.0000x reference)
//
#include <hip/hip_runtime.h>
#include <cstdint>
#include <cstddef>

#define ND 128
#define NK 1024
#define NROWS 8192
#define RANK 8

#define OFF_EMB 8192
#define OFF_CS  139264
#define OFF_EMA 140288

// workspace byte offsets
#define WSB_EBH 33816576u             // E_hi  bf16, MFMA-fragment-major, 256KB
#define WSB_EBM 34078720u             // E_mid bf16, fragment-major
#define WSB_NTOT 34340864u
#define WSB_IDX  34341120u            // 8192 int

typedef __attribute__((ext_vector_type(8))) short bf16x8;
typedef __attribute__((ext_vector_type(4))) float f32x4;

__device__ __forceinline__ short f2bf(float v) {
  union { float f; unsigned u; } a; a.f = v;
  unsigned r = a.u + 0x7fffu + ((a.u >> 16) & 1u);
  return (short)(r >> 16);
}
__device__ __forceinline__ float bf2f(short s) {
  union { unsigned u; float f; } a; a.u = ((unsigned)(unsigned short)s) << 16;
  return a.f;
}

// ---------------------------------------------------------------------------
// kEB: b<128: E -> EBh/EBm bf16 splits, MFMA-fragment-major.
//      b==128: ntot = 0.99*sum(cs) + 0.01*8192.
// ---------------------------------------------------------------------------
__global__ __launch_bounds__(256)
void kEB(const float* __restrict__ E, const float* __restrict__ cs,
         short* __restrict__ EBh, short* __restrict__ EBm,
         float* __restrict__ ntot)
{
  __shared__ float red[4];
  const int b   = blockIdx.x;
  const int tid = threadIdx.x;
  if (b < 128) {
    const int f4   = b * 256 + tid;          // float4 index, 0..32767
    const int flat = f4 * 4;
    const int k  = flat >> 7;
    const int i0 = flat & 127;
    const float4 v = *(const float4*)(E + flat);
    short h[4], m[4];
    const float vf[4] = {v.x, v.y, v.z, v.w};
    #pragma unroll
    for (int c = 0; c < 4; ++c) {
      h[c] = f2bf(vf[c]);
      m[c] = f2bf(vf[c] - bf2f(h[c]));
    }
    const int ktile = k >> 4, ks = i0 >> 5, hi = (i0 >> 3) & 3, e = i0 & 7;
    const size_t off = ((size_t)(ktile * 4 + ks) * 64 + ((k & 15) + (hi << 4))) * 8 + e;
    *(short4*)(EBh + off) = make_short4(h[0], h[1], h[2], h[3]);
    *(short4*)(EBm + off) = make_short4(m[0], m[1], m[2], m[3]);
  } else {
    float s = cs[tid] + cs[tid + 256] + cs[tid + 512] + cs[tid + 768];
    #pragma unroll
    for (int off = 32; off; off >>= 1) s += __shfl_xor(s, off);
    if ((tid & 63) == 0) red[tid >> 6] = s;
    __syncthreads();
    if (tid == 0)
      ntot[0] = fmaf(0.99f, (red[0] + red[1]) + (red[2] + red[3]), 81.92f);
  }
}

// ---------------------------------------------------------------------------
// kFused: 1024 blocks x 128 thr (2 waves). Block owns 8 n.
// Phase A (chol, BARRIER-FREE): wave w factors n = nb+4w..nb+4w+3 with
//   register/shfl pivoted chol-8 — W16 staged same-wave to LDS (lgkmcnt
//   ordering only), L values exchanged via __shfl within 16-lane groups.
//   L bf16 h/m splits + u go to LDS; Lt/u never touch global memory.
// One __syncthreads at the phase boundary.
// Phase B (dist): identical to R12/R14 kDist, A-frags from LDS.
// ---------------------------------------------------------------------------
__global__ __launch_bounds__(128, 2)
void kFused(const float* __restrict__ z, const float* __restrict__ G,
            const short* __restrict__ EBh, const short* __restrict__ EBm,
            float* __restrict__ outIdxF, int* __restrict__ outIdxI)
{
  __shared__ short sLh[8][8][136];     // 17408 B
  __shared__ short sLm[8][8][136];     // 17408 B
  __shared__ float sW[2][16][17];      // 2176 B (per-wave tile)
  __shared__ float sU[8][8];
  __shared__ float sV[2][8];
  __shared__ int   sI[2][8];

  const int tid  = threadIdx.x;
  const int lane = tid & 63;
  const int w    = tid >> 6;
  const int nb   = blockIdx.x * 8;
  const int t    = lane & 15;
  const int grp  = lane & 48;          // 16-lane group base

  // ================= phase A: barrier-free chol of own 4 n =================
  float2 qA[16], qB[16];
  float2 zA, zB;

  auto LOADROWS = [&](int nloc, float2* q, float2& zz) {
    const size_t gb = (size_t)(nb + nloc) * (ND * ND);
    #pragma unroll
    for (int rr = 0; rr < 16; ++rr)
      q[rr] = *(const float2*)(G + gb + (size_t)(8 * rr) * ND + lane * 2);
    zz = *(const float2*)(z + (size_t)(nb + nloc) * ND + lane * 2);
  };

  auto PROCESS = [&](int nloc, const float2* q, float2 zz) {
    // ---- stage W16 (same-wave LDS write->read; no block barrier) ----
    if ((lane & 3) == 0) {
      const int sl = lane >> 2;          // 0..15
      #pragma unroll
      for (int rr = 0; rr < 16; ++rr)
        sW[w][rr][sl] = q[rr].x;         // W[rr][sl] = G_row_rr[8*sl]
    }
    __builtin_amdgcn_wave_barrier();
    asm volatile("" ::: "memory");

    // ---- register pivoted chol-8 (shfl co-op in 16-lane groups) ----
    float lt[8];
    int piv[8];
    float dg = sW[w][t][t];
    #pragma unroll
    for (int j = 0; j < 8; ++j) {
      float mv = dg; int p = t;
      #pragma unroll
      for (int off = 1; off < 16; off <<= 1) {
        const float ov = __shfl_xor(mv, off);
        const int   op = __shfl_xor(p, off);
        if (ov > mv || (ov == mv && op < p)) { mv = ov; p = op; }
      }
      piv[j] = p;
      const float s = (mv > 1e-12f) ? (1.0f / sqrtf(mv)) : 0.0f;
      float c = sW[w][t][p];
      #pragma unroll
      for (int r = 0; r < j; ++r)
        c -= lt[r] * __shfl(lt[r], grp + p);
      const float l = c * s;
      lt[j] = l;
      dg -= l * l;
      if (t == p) dg = -3.4e38f;
    }

    // ---- L8 rows via group shfl (wave-uniform values) ----
    float L8[8][8];
    #pragma unroll
    for (int r = 0; r < 8; ++r)
      #pragma unroll
      for (int qq = 0; qq <= r; ++qq)
        L8[r][qq] = __shfl(lt[qq], grp + piv[r]);
    float invd[8];
    #pragma unroll
    for (int r = 0; r < 8; ++r)
      invd[r] = (L8[r][r] > 1e-12f) ? (1.0f / L8[r][r]) : 0.0f;

    // ---- per-lane forward substitution (static piv-select, rule #20) ----
    float x0[8], x1[8];
    #pragma unroll
    for (int r = 0; r < 8; ++r) {
      float a0 = 0.f, a1 = 0.f;
      #pragma unroll
      for (int rr = 0; rr < 16; ++rr) {
        const bool sel = (piv[r] == rr);
        a0 = sel ? q[rr].x : a0;
        a1 = sel ? q[rr].y : a1;
      }
      #pragma unroll
      for (int qq = 0; qq < r; ++qq) {
        a0 -= L8[r][qq] * x0[qq];
        a1 -= L8[r][qq] * x1[qq];
      }
      x0[r] = a0 * invd[r];
      x1[r] = a1 * invd[r];
    }

    // ---- bf16 h/m splits -> LDS [nloc][r][i], i = 2*lane, 2*lane+1 ----
    #pragma unroll
    for (int r = 0; r < RANK; ++r) {
      const short h0 = f2bf(x0[r]);
      const short m0 = f2bf(x0[r] - bf2f(h0));
      const short h1 = f2bf(x1[r]);
      const short m1 = f2bf(x1[r] - bf2f(h1));
      *(short2*)(&sLh[nloc][r][lane * 2]) = make_short2(h0, h1);
      *(short2*)(&sLm[nloc][r][lane * 2]) = make_short2(m0, m1);
    }
    // ---- u = L^T z ----
    float pu[RANK];
    #pragma unroll
    for (int r = 0; r < RANK; ++r) pu[r] = x0[r] * zz.x + x1[r] * zz.y;
    #pragma unroll
    for (int off = 32; off; off >>= 1) {
      #pragma unroll
      for (int r = 0; r < RANK; ++r) pu[r] += __shfl_xor(pu[r], off);
    }
    if (lane == 0) {
      #pragma unroll
      for (int r = 0; r < RANK; ++r) sU[nloc][r] = pu[r];
    }
  };

  {
    const int n0 = 4 * w;
    LOADROWS(n0 + 0, qA, zA);
    LOADROWS(n0 + 1, qB, zB);
    PROCESS(n0 + 0, qA, zA);
    LOADROWS(n0 + 2, qA, zA);
    PROCESS(n0 + 1, qB, zB);
    LOADROWS(n0 + 3, qB, zB);
    PROCESS(n0 + 2, qA, zA);
    PROCESS(n0 + 3, qB, zB);
  }
  __syncthreads();   // single phase boundary

  // ================= phase B: distances + argmin =================
  const int kh = w;

  bf16x8 Ah[4][4], Am[4][4];
  #pragma unroll
  for (int p = 0; p < 4; ++p) {
    const int nloc = p * 2 + ((lane & 15) >> 3);
    const int r    = lane & 7;
    const int ioff = (lane >> 4) * 8;
    #pragma unroll
    for (int ks = 0; ks < 4; ++ks) {
      Ah[p][ks] = *(const bf16x8*)(&sLh[nloc][r][ioff + ks * 32]);
      Am[p][ks] = *(const bf16x8*)(&sLm[nloc][r][ioff + ks * 32]);
    }
  }
  float uv[4][4];
  #pragma unroll
  for (int p = 0; p < 4; ++p)
    #pragma unroll
    for (int reg = 0; reg < 4; ++reg) {
      const int nr = (lane >> 4) * 4 + reg;
      uv[p][reg] = sU[p * 2 + (nr >> 3)][nr & 7];
    }

  float bv[4]; int bi[4];
  #pragma unroll
  for (int p = 0; p < 4; ++p) { bv[p] = 3.4e38f; bi[p] = 1 << 30; }

  bf16x8 B0h[4], B0m[4], B1h[4], B1m[4];

  auto LOADB = [&](bf16x8* Bh_, bf16x8* Bm_, int t_) {
    #pragma unroll
    for (int ks = 0; ks < 4; ++ks) {
      const size_t o = ((size_t)(t_ * 4 + ks) * 64 + lane) * 8;
      Bh_[ks] = *(const bf16x8*)(EBh + o);
      Bm_[ks] = *(const bf16x8*)(EBm + o);
    }
  };

  auto COMPUTE = [&](const bf16x8* Bh_, const bf16x8* Bm_, int t_) {
    f32x4 C[4];
    #pragma unroll
    for (int p = 0; p < 4; ++p) C[p] = (f32x4){0.f, 0.f, 0.f, 0.f};
    #pragma unroll
    for (int ks = 0; ks < 4; ++ks) {
      #pragma unroll
      for (int p = 0; p < 4; ++p)
        C[p] = __builtin_amdgcn_mfma_f32_16x16x32_bf16(Ah[p][ks], Bh_[ks], C[p], 0, 0, 0);
      #pragma unroll
      for (int p = 0; p < 4; ++p)
        C[p] = __builtin_amdgcn_mfma_f32_16x16x32_bf16(Ah[p][ks], Bm_[ks], C[p], 0, 0, 0);
      #pragma unroll
      for (int p = 0; p < 4; ++p)
        C[p] = __builtin_amdgcn_mfma_f32_16x16x32_bf16(Am[p][ks], Bh_[ks], C[p], 0, 0, 0);
    }
    const int kcol = t_ * 16 + (lane & 15);
    #pragma unroll
    for (int p = 0; p < 4; ++p) {
      float s = 0.f;
      #pragma unroll
      for (int reg = 0; reg < 4; ++reg) {
        const float d = uv[p][reg] - C[p][reg];
        s = fmaf(d, d, s);
      }
      s += __shfl_xor(s, 16);
      if (s < bv[p] || (s == bv[p] && kcol < bi[p])) { bv[p] = s; bi[p] = kcol; }
    }
  };

  const int t0 = kh * 32;
  LOADB(B0h, B0m, t0);
  for (int tt = 0; tt < 32; tt += 2) {
    LOADB(B1h, B1m, t0 + tt + 1);
    COMPUTE(B0h, B0m, t0 + tt);
    if (tt + 2 < 32) LOADB(B0h, B0m, t0 + tt + 2);
    COMPUTE(B1h, B1m, t0 + tt + 1);
  }

  #pragma unroll
  for (int off = 1; off < 16; off <<= 1) {
    #pragma unroll
    for (int p = 0; p < 4; ++p) {
      const float ov = __shfl_xor(bv[p], off);
      const int   oi = __shfl_xor(bi[p], off);
      if (ov < bv[p] || (ov == bv[p] && oi < bi[p])) { bv[p] = ov; bi[p] = oi; }
    }
  }

  #pragma unroll
  for (int p = 0; p < 4; ++p) {
    if (lane == 0)  { sV[kh][p * 2 + 0] = bv[p]; sI[kh][p * 2 + 0] = bi[p]; }
    if (lane == 32) { sV[kh][p * 2 + 1] = bv[p]; sI[kh][p * 2 + 1] = bi[p]; }
  }
  __syncthreads();

  if (tid < 8) {
    const float v0 = sV[0][tid], v1 = sV[1][tid];
    const int   j0 = sI[0][tid], j1 = sI[1][tid];
    const int   bidx = (v1 < v0) ? j1 : j0;   // khalf0 k's smaller: ties -> 0
    outIdxF[nb + tid] = (float)bidx;
    outIdxI[nb + tid] = bidx;
  }
}

// ---------------------------------------------------------------------------
// kGF: unchanged. Block k: ballot-gather + EMA outputs, no atomics.
// ---------------------------------------------------------------------------
__global__ __launch_bounds__(256)
void kGF(const float* __restrict__ z, const int* __restrict__ idx,
         const float* __restrict__ cs, const float* __restrict__ ema,
         const float* __restrict__ ntot, float* __restrict__ outCs,
         float* __restrict__ outEmb, float* __restrict__ outEma)
{
  __shared__ float sAcc[4][128];
  __shared__ float sCnt[4];
  const int k    = blockIdx.x;
  const int tid  = threadIdx.x;
  const int wave = tid >> 6, lane = tid & 63;

  float a0 = 0.f, a1 = 0.f;
  int cnt = 0;
  const int nbase = wave * 2048;
  #pragma unroll 2
  for (int c4 = 0; c4 < 8; ++c4) {
    const int b0 = nbase + c4 * 256 + lane;
    const int i0 = idx[b0];
    const int i1 = idx[b0 + 64];
    const int i2 = idx[b0 + 128];
    const int i3 = idx[b0 + 192];
    #pragma unroll
    for (int q = 0; q < 4; ++q) {
      const int iv = (q == 0) ? i0 : (q == 1) ? i1 : (q == 2) ? i2 : i3;
      unsigned long long m = __ballot(iv == k);
      cnt += (int)__popcll(m);
      const int cbase = nbase + c4 * 256 + q * 64;
      while (m) {
        const int j = __builtin_ctzll(m); m &= m - 1;
        const int n = cbase + j;
        a0 += z[(size_t)n * ND + lane];
        a1 += z[(size_t)n * ND + lane + 64];
      }
    }
  }
  sAcc[wave][lane] = a0;
  sAcc[wave][lane + 64] = a1;
  if (lane == 0) sCnt[wave] = (float)cnt;
  __syncthreads();

  if (wave == 0) {
    const float d0 = ((sAcc[0][lane] + sAcc[1][lane]) + sAcc[2][lane]) + sAcc[3][lane];
    const float d1 = ((sAcc[0][lane + 64] + sAcc[1][lane + 64]) + sAcc[2][lane + 64]) + sAcc[3][lane + 64];
    const float count = ((sCnt[0] + sCnt[1]) + sCnt[2]) + sCnt[3];
    const float nt = ntot[0];
    const float v  = cs[k] * 0.99f + 0.01f * count;
    const float sm = (v + 1e-5f) / (nt + 1024.0f * 1e-5f) * nt;
    const size_t e0 = (size_t)k * ND + lane;
    const size_t e1 = e0 + 64;
    const float nv0 = ema[e0] * 0.99f + 0.01f * d0;
    const float nv1 = ema[e1] * 0.99f + 0.01f * d1;
    outEma[e0] = nv0; outEmb[e0] = nv0 / sm;
    outEma[e1] = nv1; outEmb[e1] = nv1 / sm;
    if (lane == 0) outCs[k] = v;
  }
}

extern "C" void kernel_launch(void* const* d_in, const int* in_sizes, int n_in,
                              void* d_out, int out_size, void* d_ws, size_t ws_size,
                              hipStream_t stream)
{
  const float* z  = (const float*)d_in[0];
  const float* G  = (const float*)d_in[1];
  const float* E  = (const float*)d_in[2];
  const float* cs = (const float*)d_in[3];
  const float* ew = (const float*)d_in[4];
  float* out = (float*)d_out;

  char* ws = (char*)d_ws;
  short* wEBh = (short*)(ws + WSB_EBH);
  short* wEBm = (short*)(ws + WSB_EBM);
  float* wNtot = (float*)(ws + WSB_NTOT);
  int*   wIdx  = (int*)(ws + WSB_IDX);

  kEB<<<129, 256, 0, stream>>>(E, cs, wEBh, wEBm, wNtot);
  kFused<<<1024, 128, 0, stream>>>(z, G, wEBh, wEBm, out, wIdx);
  kGF<<<1024, 256, 0, stream>>>(z, wIdx, cs, ew, wNtot,
                                out + OFF_CS, out + OFF_EMB, out + OFF_EMA);
}

// Round 17
// 84.402 us; speedup vs baseline: 1.0781x; 1.0781x over previous
//
#include <hip/hip_runtime.h>
#include <cstdint>
#include <cstddef>

#define ND 128
#define NK 1024
#define NROWS 8192
#define RANK 8

#define OFF_EMB 8192
#define OFF_CS  139264
#define OFF_EMA 140288

// workspace byte offsets
#define WSB_LTH 0u                    // Lt_hi  bf16 [8192][8][128]
#define WSB_LTM 16777216u             // Lt_mid bf16
#define WSB_U   33554432u             // u f32 [8192][8]
#define WSB_EBH 33816576u             // E_hi  bf16, MFMA-fragment-major, 256KB
#define WSB_EBM 34078720u             // E_mid bf16, fragment-major
#define WSB_NTOT 34340864u
#define WSB_IDX  34341120u            // 8192 int

typedef __attribute__((ext_vector_type(8))) short bf16x8;
typedef __attribute__((ext_vector_type(4))) float f32x4;

__device__ __forceinline__ short f2bf(float v) {
  union { float f; unsigned u; } a; a.f = v;
  unsigned r = a.u + 0x7fffu + ((a.u >> 16) & 1u);
  return (short)(r >> 16);
}
__device__ __forceinline__ float bf2f(short s) {
  union { unsigned u; float f; } a; a.u = ((unsigned)(unsigned short)s) << 16;
  return a.f;
}

// ---------------------------------------------------------------------------
// kPre (R12 configuration — best measured):
//  b < 2048 : Nystrom rank-8 factor of G_n, 1 wave per n (4 n / block).
//    Read 16 fixed rows S16={0,8,..,120} (coalesced, ONE latency round) ->
//    LDS. W16[t][s]=rows[t][8s]. Greedy pivoted chol-8 of W16 (16-lane co-op,
//    LDS-resident, no HBM in the chain). L = C8 * L8^-T fwd substitution.
//    Emit bf16 h/m splits of L^T ([n][r][i]) + u = L^T z (f32).
//  b 2048..2175 : E -> EBh/EBm bf16 splits, MFMA-fragment-major.
//  b == 2176    : ntot = 0.99*sum(cs) + 0.01*8192.
// ---------------------------------------------------------------------------
__global__ __launch_bounds__(256)
void kPre(const float* __restrict__ z, const float* __restrict__ G,
          const float* __restrict__ E, const float* __restrict__ cs,
          short* __restrict__ Lth, short* __restrict__ Ltm,
          float* __restrict__ uPack,
          short* __restrict__ EBh, short* __restrict__ EBm,
          float* __restrict__ ntot)
{
  __shared__ float sRows[4][16][132];   // 33.8 KB: per-wave 16 rows of G
  __shared__ float sLW[4][16][9];       // pivoted-chol L of W16
  __shared__ float red[4];
  const int b   = blockIdx.x;
  const int tid = threadIdx.x;

  if (b < 2048) {
    const int w = tid >> 6, lane = tid & 63;
    const int t = lane & 15;
    const int n = b * 4 + w;
    const size_t gb = (size_t)n * (ND * ND);

    // ---- load 16 rows (one parallel latency round), stash to LDS ----
    float r0[16], r1[16];
    #pragma unroll
    for (int rr = 0; rr < 16; ++rr) {
      r0[rr] = G[gb + (size_t)(8 * rr) * ND + lane];
      r1[rr] = G[gb + (size_t)(8 * rr) * ND + 64 + lane];
    }
    #pragma unroll
    for (int rr = 0; rr < 16; ++rr) {
      sRows[w][rr][lane]      = r0[rr];
      sRows[w][rr][lane + 64] = r1[rr];
    }
    __syncthreads();

    // ---- pivoted chol-8 of W16 (W[t][s] = rows[t][8s]); 16-lane co-op ----
    int piv[8];
    float dg = sRows[w][t][8 * t];
    #pragma unroll
    for (int j = 0; j < 8; ++j) {
      float mv = dg; int p = t;
      #pragma unroll
      for (int off = 1; off < 16; off <<= 1) {
        const float ov = __shfl_xor(mv, off);
        const int   op = __shfl_xor(p, off);
        if (ov > mv || (ov == mv && op < p)) { mv = ov; p = op; }
      }
      piv[j] = p;
      const float s = (mv > 1e-12f) ? (1.0f / sqrtf(mv)) : 0.0f;
      float c = sRows[w][t][8 * p];
      #pragma unroll
      for (int r = 0; r < j; ++r)
        c -= sLW[w][t][r] * sLW[w][p][r];
      const float l = c * s;
      if (lane < 16) sLW[w][t][j] = l;
      dg -= l * l;
      if (t == p) dg = -3.4e38f;
      __syncthreads();
    }

    // ---- L8 (wave-uniform) + per-lane forward substitution ----
    float L8[8][8];
    #pragma unroll
    for (int r = 0; r < 8; ++r)
      #pragma unroll
      for (int q = 0; q <= r; ++q)
        L8[r][q] = sLW[w][piv[r]][q];
    float invd[8];
    #pragma unroll
    for (int r = 0; r < 8; ++r)
      invd[r] = (L8[r][r] > 1e-12f) ? (1.0f / L8[r][r]) : 0.0f;

    float x0[8], x1[8];
    #pragma unroll
    for (int r = 0; r < 8; ++r) {
      float a0 = sRows[w][piv[r]][lane];
      float a1 = sRows[w][piv[r]][lane + 64];
      #pragma unroll
      for (int q = 0; q < r; ++q) {
        a0 -= L8[r][q] * x0[q];
        a1 -= L8[r][q] * x1[q];
      }
      x0[r] = a0 * invd[r];
      x1[r] = a1 * invd[r];
    }

    // ---- bf16 h/m splits of L^T: [n][r][i] ----
    const int i0 = lane, i1 = lane + 64;
    #pragma unroll
    for (int r = 0; r < RANK; ++r) {
      const size_t o0 = ((size_t)n * 8 + r) * 128 + i0;
      const size_t o1 = ((size_t)n * 8 + r) * 128 + i1;
      short h = f2bf(x0[r]);
      short m = f2bf(x0[r] - bf2f(h));
      Lth[o0] = h; Ltm[o0] = m;
      h = f2bf(x1[r]);
      m = f2bf(x1[r] - bf2f(h));
      Lth[o1] = h; Ltm[o1] = m;
    }
    // ---- u = L^T z ----
    const float z0 = z[(size_t)n * ND + i0];
    const float z1 = z[(size_t)n * ND + i1];
    float pu[RANK];
    #pragma unroll
    for (int r = 0; r < RANK; ++r) pu[r] = x0[r] * z0 + x1[r] * z1;
    #pragma unroll
    for (int off = 32; off; off >>= 1) {
      #pragma unroll
      for (int r = 0; r < RANK; ++r) pu[r] += __shfl_xor(pu[r], off);
    }
    if (lane == 0) {
      #pragma unroll
      for (int r = 0; r < RANK; ++r) uPack[(size_t)n * 8 + r] = pu[r];
    }
  } else if (b < 2176) {
    // E splits -> fragment-major EB
    const int f4   = (b - 2048) * 256 + tid;   // float4 index, 0..32767
    const int flat = f4 * 4;
    const int k  = flat >> 7;
    const int i0 = flat & 127;
    const float4 v = *(const float4*)(E + flat);
    short h[4], m[4];
    const float vf[4] = {v.x, v.y, v.z, v.w};
    #pragma unroll
    for (int c = 0; c < 4; ++c) {
      h[c] = f2bf(vf[c]);
      m[c] = f2bf(vf[c] - bf2f(h[c]));
    }
    const int ktile = k >> 4, ks = i0 >> 5, hi = (i0 >> 3) & 3, e = i0 & 7;
    const size_t off = ((size_t)(ktile * 4 + ks) * 64 + ((k & 15) + (hi << 4))) * 8 + e;
    *(short4*)(EBh + off) = make_short4(h[0], h[1], h[2], h[3]);
    *(short4*)(EBm + off) = make_short4(m[0], m[1], m[2], m[3]);
  } else {
    float s = cs[tid] + cs[tid + 256] + cs[tid + 512] + cs[tid + 768];
    #pragma unroll
    for (int off = 32; off; off >>= 1) s += __shfl_xor(s, off);
    if ((tid & 63) == 0) red[tid >> 6] = s;
    __syncthreads();
    if (tid == 0)
      ntot[0] = fmaf(0.99f, (red[0] + red[1]) + (red[2] + red[3]), 81.92f);
  }
}

// ---------------------------------------------------------------------------
// kDist: 1024 blocks x 128 threads (2 waves); block owns 8 n; wave kh owns
// k-half. 2 waves/SIMD: one wave's MFMA issue hides the other's L2 latency +
// epilogue. A = L^T hoisted, B direct from fragment-major EB, register
// double-buffer, 3-term split MFMA (hh+hm+mh), first-index tie-break.
// ---------------------------------------------------------------------------
__global__ __launch_bounds__(128, 2)
void kDist(const short* __restrict__ Lth, const short* __restrict__ Ltm,
           const float* __restrict__ uPack,
           const short* __restrict__ EBh, const short* __restrict__ EBm,
           float* __restrict__ outIdxF, int* __restrict__ outIdxI)
{
  __shared__ float sV[2][8];
  __shared__ int   sI[2][8];

  const int tid  = threadIdx.x;
  const int lane = tid & 63;
  const int kh   = tid >> 6;            // wave = k-half
  const int nb   = blockIdx.x * 8;

  bf16x8 Ah[4][4], Am[4][4];
  #pragma unroll
  for (int p = 0; p < 4; ++p) {
    const int nloc = p * 2 + ((lane & 15) >> 3);
    const size_t rowb = ((size_t)(nb + nloc) * 8 + (lane & 7)) * 128 + ((lane >> 4) * 8);
    #pragma unroll
    for (int ks = 0; ks < 4; ++ks) {
      Ah[p][ks] = *(const bf16x8*)(Lth + rowb + ks * 32);
      Am[p][ks] = *(const bf16x8*)(Ltm + rowb + ks * 32);
    }
  }
  float uv[4][4];
  #pragma unroll
  for (int p = 0; p < 4; ++p)
    #pragma unroll
    for (int reg = 0; reg < 4; ++reg) {
      const int nr = (lane >> 4) * 4 + reg;
      uv[p][reg] = uPack[(size_t)(nb + p * 2 + (nr >> 3)) * 8 + (nr & 7)];
    }

  float bv[4]; int bi[4];
  #pragma unroll
  for (int p = 0; p < 4; ++p) { bv[p] = 3.4e38f; bi[p] = 1 << 30; }

  bf16x8 B0h[4], B0m[4], B1h[4], B1m[4];

  auto LOADB = [&](bf16x8* Bh_, bf16x8* Bm_, int t_) {
    #pragma unroll
    for (int ks = 0; ks < 4; ++ks) {
      const size_t o = ((size_t)(t_ * 4 + ks) * 64 + lane) * 8;
      Bh_[ks] = *(const bf16x8*)(EBh + o);
      Bm_[ks] = *(const bf16x8*)(EBm + o);
    }
  };

  auto COMPUTE = [&](const bf16x8* Bh_, const bf16x8* Bm_, int t_) {
    f32x4 C[4];
    #pragma unroll
    for (int p = 0; p < 4; ++p) C[p] = (f32x4){0.f, 0.f, 0.f, 0.f};
    #pragma unroll
    for (int ks = 0; ks < 4; ++ks) {
      #pragma unroll
      for (int p = 0; p < 4; ++p)
        C[p] = __builtin_amdgcn_mfma_f32_16x16x32_bf16(Ah[p][ks], Bh_[ks], C[p], 0, 0, 0);
      #pragma unroll
      for (int p = 0; p < 4; ++p)
        C[p] = __builtin_amdgcn_mfma_f32_16x16x32_bf16(Ah[p][ks], Bm_[ks], C[p], 0, 0, 0);
      #pragma unroll
      for (int p = 0; p < 4; ++p)
        C[p] = __builtin_amdgcn_mfma_f32_16x16x32_bf16(Am[p][ks], Bh_[ks], C[p], 0, 0, 0);
    }
    const int kcol = t_ * 16 + (lane & 15);
    #pragma unroll
    for (int p = 0; p < 4; ++p) {
      float s = 0.f;
      #pragma unroll
      for (int reg = 0; reg < 4; ++reg) {
        const float d = uv[p][reg] - C[p][reg];
        s = fmaf(d, d, s);
      }
      s += __shfl_xor(s, 16);
      if (s < bv[p] || (s == bv[p] && kcol < bi[p])) { bv[p] = s; bi[p] = kcol; }
    }
  };

  const int t0 = kh * 32;
  LOADB(B0h, B0m, t0);
  for (int t = 0; t < 32; t += 2) {
    LOADB(B1h, B1m, t0 + t + 1);
    COMPUTE(B0h, B0m, t0 + t);
    if (t + 2 < 32) LOADB(B0h, B0m, t0 + t + 2);
    COMPUTE(B1h, B1m, t0 + t + 1);
  }

  #pragma unroll
  for (int off = 1; off < 16; off <<= 1) {
    #pragma unroll
    for (int p = 0; p < 4; ++p) {
      const float ov = __shfl_xor(bv[p], off);
      const int   oi = __shfl_xor(bi[p], off);
      if (ov < bv[p] || (ov == bv[p] && oi < bi[p])) { bv[p] = ov; bi[p] = oi; }
    }
  }

  #pragma unroll
  for (int p = 0; p < 4; ++p) {
    if (lane == 0)  { sV[kh][p * 2 + 0] = bv[p]; sI[kh][p * 2 + 0] = bi[p]; }
    if (lane == 32) { sV[kh][p * 2 + 1] = bv[p]; sI[kh][p * 2 + 1] = bi[p]; }
  }
  __syncthreads();

  if (tid < 8) {
    const float v0 = sV[0][tid], v1 = sV[1][tid];
    const int   j0 = sI[0][tid], j1 = sI[1][tid];
    const int   bidx = (v1 < v0) ? j1 : j0;   // khalf0 k's smaller: ties -> 0
    outIdxF[nb + tid] = (float)bidx;
    outIdxI[nb + tid] = bidx;
  }
}

// ---------------------------------------------------------------------------
// kGF: block k: ballot-gather + EMA outputs, no atomics.
// ---------------------------------------------------------------------------
__global__ __launch_bounds__(256)
void kGF(const float* __restrict__ z, const int* __restrict__ idx,
         const float* __restrict__ cs, const float* __restrict__ ema,
         const float* __restrict__ ntot, float* __restrict__ outCs,
         float* __restrict__ outEmb, float* __restrict__ outEma)
{
  __shared__ float sAcc[4][128];
  __shared__ float sCnt[4];
  const int k    = blockIdx.x;
  const int tid  = threadIdx.x;
  const int wave = tid >> 6, lane = tid & 63;

  float a0 = 0.f, a1 = 0.f;
  int cnt = 0;
  const int nbase = wave * 2048;
  #pragma unroll 2
  for (int c4 = 0; c4 < 8; ++c4) {
    const int b0 = nbase + c4 * 256 + lane;
    const int i0 = idx[b0];
    const int i1 = idx[b0 + 64];
    const int i2 = idx[b0 + 128];
    const int i3 = idx[b0 + 192];
    #pragma unroll
    for (int q = 0; q < 4; ++q) {
      const int iv = (q == 0) ? i0 : (q == 1) ? i1 : (q == 2) ? i2 : i3;
      unsigned long long m = __ballot(iv == k);
      cnt += (int)__popcll(m);
      const int cbase = nbase + c4 * 256 + q * 64;
      while (m) {
        const int j = __builtin_ctzll(m); m &= m - 1;
        const int n = cbase + j;
        a0 += z[(size_t)n * ND + lane];
        a1 += z[(size_t)n * ND + lane + 64];
      }
    }
  }
  sAcc[wave][lane] = a0;
  sAcc[wave][lane + 64] = a1;
  if (lane == 0) sCnt[wave] = (float)cnt;
  __syncthreads();

  if (wave == 0) {
    const float d0 = ((sAcc[0][lane] + sAcc[1][lane]) + sAcc[2][lane]) + sAcc[3][lane];
    const float d1 = ((sAcc[0][lane + 64] + sAcc[1][lane + 64]) + sAcc[2][lane + 64]) + sAcc[3][lane + 64];
    const float count = ((sCnt[0] + sCnt[1]) + sCnt[2]) + sCnt[3];
    const float nt = ntot[0];
    const float v  = cs[k] * 0.99f + 0.01f * count;
    const float sm = (v + 1e-5f) / (nt + 1024.0f * 1e-5f) * nt;
    const size_t e0 = (size_t)k * ND + lane;
    const size_t e1 = e0 + 64;
    const float nv0 = ema[e0] * 0.99f + 0.01f * d0;
    const float nv1 = ema[e1] * 0.99f + 0.01f * d1;
    outEma[e0] = nv0; outEmb[e0] = nv0 / sm;
    outEma[e1] = nv1; outEmb[e1] = nv1 / sm;
    if (lane == 0) outCs[k] = v;
  }
}

extern "C" void kernel_launch(void* const* d_in, const int* in_sizes, int n_in,
                              void* d_out, int out_size, void* d_ws, size_t ws_size,
                              hipStream_t stream)
{
  const float* z  = (const float*)d_in[0];
  const float* G  = (const float*)d_in[1];
  const float* E  = (const float*)d_in[2];
  const float* cs = (const float*)d_in[3];
  const float* ew = (const float*)d_in[4];
  float* out = (float*)d_out;

  char* ws = (char*)d_ws;
  short* wLth = (short*)(ws + WSB_LTH);
  short* wLtm = (short*)(ws + WSB_LTM);
  float* wU   = (float*)(ws + WSB_U);
  short* wEBh = (short*)(ws + WSB_EBH);
  short* wEBm = (short*)(ws + WSB_EBM);
  float* wNtot = (float*)(ws + WSB_NTOT);
  int*   wIdx  = (int*)(ws + WSB_IDX);

  kPre<<<2177, 256, 0, stream>>>(z, G, E, cs, wLth, wLtm, wU,
                                 wEBh, wEBm, wNtot);
  kDist<<<1024, 128, 0, stream>>>(wLth, wLtm, wU, wEBh, wEBm, out, wIdx);
  kGF<<<1024, 256, 0, stream>>>(z, wIdx, cs, ew, wNtot,
                                out + OFF_CS, out + OFF_EMB, out + OFF_EMA);
}